// Round 4
// baseline (299.874 us; speedup 1.0000x reference)
//
#include <hip/hip_runtime.h>

typedef __bf16 bf16_t;
typedef bf16_t bf16x8 __attribute__((ext_vector_type(8)));
typedef _Float16 f16_t;
typedef __fp16 hf16x2 __attribute__((ext_vector_type(2)));   // cvt_pkrtz return type
typedef f16_t f16x8 __attribute__((ext_vector_type(8)));
typedef float floatx4 __attribute__((ext_vector_type(4)));
typedef float floatx16 __attribute__((ext_vector_type(16)));

#define S_LEN 2048
#define DIM 768
#define NH 16
#define HD 48
#define HDP 64
#define BHEADS 64          // B * NH
#define ATT_SCALE 0.14433756729740643f  // 1/sqrt(48)
#define W_ELEMS (DIM * DIM)

typedef unsigned short u16;
typedef unsigned int u32;

__device__ __forceinline__ u16 f2b(float f) {
  union { float f; u32 i; } z; z.f = f;
  u32 i = z.i;
  return (u16)((i + 0x7fffu + ((i >> 16) & 1u)) >> 16);  // RNE
}
__device__ __forceinline__ u32 pack2(float a, float b) {
  return (u32)f2b(a) | ((u32)f2b(b) << 16);
}
__device__ __forceinline__ u32 pkrtz2(float a, float b) {   // 2x f32 -> packed f16
  union { hf16x2 h; u32 u; } z;
  z.h = __builtin_amdgcn_cvt_pkrtz(a, b);
  return z.u;
}
// v_permlane32_swap_b32: a' = [a.lanes0-31, b.lanes0-31]; b' = [a.lanes32-63, b.lanes32-63]
__device__ __forceinline__ void pl32swap(u32& a, u32& b) {
  asm("v_permlane32_swap_b32 %0, %1" : "+v"(a), "+v"(b));
}

// ---------------------------------------------------------------------------
// fp32 -> bf16 bulk convert, 8 floats/thread. Used for x (3072 blocks).
// ---------------------------------------------------------------------------
__global__ __launch_bounds__(256) void cvt_f32_bf16(
    const float* __restrict__ src, u16* __restrict__ dst)
{
  int idx = blockIdx.x * 256 + threadIdx.x;
  const float4* s = (const float4*)src;
  float4 a = s[idx * 2], b = s[idx * 2 + 1];
  *(uint4*)&dst[(size_t)idx * 8] =
      make_uint4(pack2(a.x, a.y), pack2(a.z, a.w), pack2(b.x, b.y), pack2(b.z, b.w));
}

// ---------------------------------------------------------------------------
// Convert the 4 weight matrices fp32 -> bf16 once per launch. grid (288, 4).
// ---------------------------------------------------------------------------
__global__ __launch_bounds__(256) void cvt_weights(
    const float* __restrict__ w0, const float* __restrict__ w1,
    const float* __restrict__ w2, const float* __restrict__ w3,
    u16* __restrict__ dst)
{
  const float* srcs[4] = {w0, w1, w2, w3};
  const float* src = srcs[blockIdx.y];
  u16* d = dst + (size_t)blockIdx.y * W_ELEMS;
  int idx = blockIdx.x * 256 + threadIdx.x;
  const float4* s = (const float4*)src;
  float4 a = s[idx * 2], b = s[idx * 2 + 1];
  *(uint4*)&d[(size_t)idx * 8] =
      make_uint4(pack2(a.x, a.y), pack2(a.z, a.w), pack2(b.x, b.y), pack2(b.z, b.w));
}

// ---------------------------------------------------------------------------
// C = (A @ W^T + bias) * scale.  A bf16 [8192][768]; W bf16 [768][768]
// (pre-converted); bias fp32. Tile 128x64, BK=32, 256 threads (4 waves).
// MFMA 16x16x32 bf16.
// OMODE 0: bf16 head-scatter [b*16+h][s][64] (Q,K; only d<48 written)
// OMODE 1: fp32 [row][768] (final output)
// OMODE 2: f16 V^T [b*16+h][d][s] via LDS-transpose epilogue
// ---------------------------------------------------------------------------
template<int OMODE>
__global__ __launch_bounds__(256) void gemm_bt(
    const u16* __restrict__ A, const u16* __restrict__ W,
    const float* __restrict__ bias, void* __restrict__ outv, float scale)
{
  // As: 128x40 (5120), Bs: 64x40 (2560); T (OMODE 2): 64x136 u16 (8704)
  __shared__ __attribute__((aligned(16))) u16 smem[8704];
  u16 (*As)[40] = (u16(*)[40])smem;
  u16 (*Bs)[40] = (u16(*)[40])(smem + 5120);

  const int tid = threadIdx.x;
  const int w = tid >> 6, lane = tid & 63, lo = lane & 15, quad = lane >> 4;
  const int bm = blockIdx.x & 63, bn = blockIdx.x >> 6;
  const int m0 = bm * 128, n0 = bn * 64;

  floatx4 acc[2][4];
#pragma unroll
  for (int mi = 0; mi < 2; mi++)
#pragma unroll
    for (int ni = 0; ni < 4; ni++) acc[mi][ni] = (floatx4){0.f, 0.f, 0.f, 0.f};

  for (int k0 = 0; k0 < DIM; k0 += 32) {
    // A tile 128x32: 512 chunks, 2/thread
#pragma unroll
    for (int it = 0; it < 2; ++it) {
      int c = tid + it * 256;
      int r = c >> 2, cc = c & 3;
      *(uint4*)&As[r][cc * 8] = *(const uint4*)&A[(size_t)(m0 + r) * DIM + k0 + cc * 8];
    }
    // W tile 64x32: 256 chunks, 1/thread (pure copy, no conversion)
    {
      int r = tid >> 2, cc = tid & 3;
      *(uint4*)&Bs[r][cc * 8] = *(const uint4*)&W[(size_t)(n0 + r) * DIM + k0 + cc * 8];
    }
    __syncthreads();
    bf16x8 af[2], bfr[4];
#pragma unroll
    for (int mi = 0; mi < 2; mi++) af[mi] = *(const bf16x8*)&As[w * 32 + mi * 16 + lo][quad * 8];
#pragma unroll
    for (int ni = 0; ni < 4; ni++) bfr[ni] = *(const bf16x8*)&Bs[ni * 16 + lo][quad * 8];
#pragma unroll
    for (int mi = 0; mi < 2; mi++)
#pragma unroll
      for (int ni = 0; ni < 4; ni++)
        acc[mi][ni] = __builtin_amdgcn_mfma_f32_16x16x32_bf16(af[mi], bfr[ni], acc[mi][ni], 0, 0, 0);
    __syncthreads();
  }

  if constexpr (OMODE == 2) {
    u16 (*T)[136] = (u16(*)[136])smem;
    u16* out = (u16*)outv;
#pragma unroll
    for (int mi = 0; mi < 2; mi++)
#pragma unroll
      for (int ni = 0; ni < 4; ni++) {
        int col = ni * 16 + lo;
        float bb = bias[n0 + col];
        float v0 = acc[mi][ni][0] + bb, v1 = acc[mi][ni][1] + bb;
        float v2 = acc[mi][ni][2] + bb, v3 = acc[mi][ni][3] + bb;
        *(uint2*)&T[col][w * 32 + mi * 16 + quad * 4] =
            make_uint2(pkrtz2(v0, v1), pkrtz2(v2, v3));
      }
    __syncthreads();
    const int b = m0 >> 11, s0 = m0 & 2047;
#pragma unroll
    for (int it = 0; it < 4; ++it) {
      int ch = tid + it * 256;
      int col = ch >> 4, sc = ch & 15;
      int gcol = n0 + col;
      int h = gcol / HD, d = gcol - h * HD;
      size_t dst = ((size_t)(b * NH + h) * HDP + d) * S_LEN + s0 + sc * 8;
      *(uint4*)&out[dst] = *(const uint4*)&T[col][sc * 8];
    }
    return;
  }

#pragma unroll
  for (int mi = 0; mi < 2; mi++)
#pragma unroll
    for (int ni = 0; ni < 4; ni++)
#pragma unroll
      for (int r = 0; r < 4; r++) {
        int row = m0 + w * 32 + mi * 16 + quad * 4 + r;
        int col = n0 + ni * 16 + lo;
        float v = (acc[mi][ni][r] + bias[col]) * scale;
        if constexpr (OMODE == 1) {
          ((float*)outv)[(size_t)row * DIM + col] = v;
        } else {
          int b = row >> 11, s = row & 2047;
          int h = col / HD, d = col - h * HD;
          ((u16*)outv)[((size_t)((b * NH + h) * S_LEN + s)) * HDP + d] = f2b(v);
        }
      }
}

// ---------------------------------------------------------------------------
// Flash attention, 32x32x16 MFMA, swapped QK^T (mfma(K,Q) -> P[key][q=l31]).
// ROUND 4: occupancy + XCD locality.
// - 4 waves x 32 q rows = 128 q rows/block; flat grid 1024 = 4 blocks/CU
//   (16 waves/CU vs 8 before). LDS 4 x 32KB = 128KB/CU.
// - XCD swizzle: xcd = flat&7 -> each XCD owns 8 consecutive bh; its K/V
//   working set = 8 x 0.5MB = 4MB = one XCD L2, so K/V re-reads across the
//   16 q-blocks of a bh are L2 hits instead of 8-XCD-spread HBM re-fetches.
// - P stays in registers: __expf -> cvt_pkrtz pairs -> v_permlane32_swap_b32
//   builds the PV A-fragment. No P LDS round-trip.
// - QK uses K-dim 48 exactly (3x16). Denominator l in f32 from UNROUNDED p;
//   epilogue completes l(q=l31) via shfl_xor(32) then fetches per-output-row
//   denom via __shfl from lane q_local (round-3 mapping fix).
// - K/V double-buffered in LDS, reg-staged issue-early/write-late (T14),
//   ONE barrier per tile. Pitches 56/72 u16 -> conflict-free ds_read_b128.
// ---------------------------------------------------------------------------
#define STG_LOAD(k0n) do {                                                     \
  _Pragma("unroll")                                                            \
  for (int it = 0; it < 3; ++it) {                                             \
    int c = tid + it * 256;                                                    \
    if (c < 384) {                                                             \
      int r = c / 6, cc = c - r * 6;                                           \
      stg[it] = *(const uint4*)&K[base + (size_t)((k0n) + r) * HDP + cc * 8];  \
    } else {                                                                   \
      int c2 = c - 384, r = c2 >> 3, cc = c2 & 7;                              \
      stg[it] = *(const uint4*)&V[base + (size_t)r * S_LEN + (k0n) + cc * 8];  \
    }                                                                          \
  }                                                                            \
} while (0)

#define STG_WRITE(bufi) do {                                                   \
  _Pragma("unroll")                                                            \
  for (int it = 0; it < 3; ++it) {                                             \
    int c = tid + it * 256;                                                    \
    if (c < 384) {                                                             \
      int r = c / 6, cc = c - r * 6;                                           \
      *(uint4*)&Ks[bufi][r][cc * 8] = stg[it];                                 \
    } else {                                                                   \
      int c2 = c - 384, r = c2 >> 3, cc = c2 & 7;                              \
      *(uint4*)&Vt[bufi][r][cc * 8] = stg[it];                                 \
    }                                                                          \
  }                                                                            \
} while (0)

__global__ __launch_bounds__(256, 4) void attn_kernel(
    const u16* __restrict__ Q, const u16* __restrict__ K,
    const u16* __restrict__ V, u16* __restrict__ O)
{
  __shared__ __attribute__((aligned(16))) u16 Ks[2][64][56];  // keys x d(<48)
  __shared__ __attribute__((aligned(16))) u16 Vt[2][64][72];  // d x keys (f16)

  const int tid = threadIdx.x;
  const int w = tid >> 6, lane = tid & 63, l31 = lane & 31, hi = lane >> 5;
  // XCD-locality swizzle: flat grid of 1024; same-bh q-blocks share an XCD.
  const int flat = blockIdx.x;
  const int xcd = flat & 7, sub = flat >> 3;          // sub in [0,128)
  const int bh = xcd * 8 + (sub >> 4);                // 8 bh per XCD
  const int q0 = (sub & 15) * 128;                    // 16 q-blocks per bh
  const size_t base = (size_t)bh * S_LEN * HDP;

  // Q fragments (B-operand of swapped QK): Q[q0+w*32+l31][ks*16+hi*8+j]
  bf16x8 qf[3];
#pragma unroll
  for (int ks = 0; ks < 3; ks++)
    qf[ks] = *(const bf16x8*)
        &Q[base + (size_t)(q0 + w * 32 + l31) * HDP + ks * 16 + hi * 8];

  floatx16 oacc[2];
#pragma unroll
  for (int nd = 0; nd < 2; nd++)
#pragma unroll
    for (int r = 0; r < 16; r++) oacc[nd][r] = 0.f;

  float l_lane = 0.f;   // f32 denom for q = l31 (this lane's key half)

  uint4 stg[3];
  STG_LOAD(0);
  STG_WRITE(0);

  for (int ti = 0; ti < 32; ++ti) {
    const int cur = ti & 1;
    if (ti < 31) STG_LOAD((ti + 1) * 64);   // in flight across the barrier (T14)
    __syncthreads();

    // K A-fragments
    bf16x8 ak[2][3];
#pragma unroll
    for (int na = 0; na < 2; na++)
#pragma unroll
      for (int ks = 0; ks < 3; ks++)
        ak[na][ks] = *(const bf16x8*)&Ks[cur][na * 32 + l31][ks * 16 + hi * 8];

    // QK^T (swapped) + exp + pack; pk[na][m] covers keys
    // na*32 + 8*(m>>1) + 4*hi + 2*(m&1) + {0,1}, all for q = l31.
    u32 pk[2][8];
    {
      floatx16 s0, s1;
#pragma unroll
      for (int r = 0; r < 16; r++) { s0[r] = 0.f; s1[r] = 0.f; }
#pragma unroll
      for (int ks = 0; ks < 3; ks++) {
        s0 = __builtin_amdgcn_mfma_f32_32x32x16_bf16(ak[0][ks], qf[ks], s0, 0, 0, 0);
        s1 = __builtin_amdgcn_mfma_f32_32x32x16_bf16(ak[1][ks], qf[ks], s1, 0, 0, 0);
      }
#pragma unroll
      for (int m = 0; m < 8; m++) {
        float a0 = __expf(s0[2 * m]), a1 = __expf(s0[2 * m + 1]);
        float b0 = __expf(s1[2 * m]), b1 = __expf(s1[2 * m + 1]);
        l_lane += (a0 + a1) + (b0 + b1);
        pk[0][m] = pkrtz2(a0, a1);
        pk[1][m] = pkrtz2(b0, b1);
      }
    }

    // O += P @ V : A-frag rebuilt in registers via permlane32_swap
#pragma unroll
    for (int kt = 0; kt < 4; kt++) {
      f16x8 bv0 = *(const f16x8*)&Vt[cur][l31][kt * 16 + hi * 8];
      f16x8 bv1 = *(const f16x8*)&Vt[cur][32 + l31][kt * 16 + hi * 8];
      const int na = kt >> 1, k4 = (kt & 1) * 4;
      u32 w0 = pk[na][k4 + 0], w2 = pk[na][k4 + 2];
      u32 w1 = pk[na][k4 + 1], w3 = pk[na][k4 + 3];
      pl32swap(w0, w2);
      pl32swap(w1, w3);
      union { u32 u[4]; f16x8 f; } af;
      af.u[0] = w0; af.u[1] = w1; af.u[2] = w2; af.u[3] = w3;
      oacc[0] = __builtin_amdgcn_mfma_f32_32x32x16_f16(af.f, bv0, oacc[0], 0, 0, 0);
      oacc[1] = __builtin_amdgcn_mfma_f32_32x32x16_f16(af.f, bv1, oacc[1], 0, 0, 0);
    }

    if (ti < 31) STG_WRITE(cur ^ 1);   // write-late into the other buffer
  }

  // epilogue: complete l(q=l31) across halves, then fetch the denominator for
  // each OUTPUT row q_local = (r&3)+8*(r>>2)+4*hi from lane q_local (hi=0
  // half holds the completed sum). O /= l, write [b][s][h*48+d].
  const int b = bh >> 4, h = bh & 15;
  float lt_full = l_lane + __shfl_xor(l_lane, 32);
#pragma unroll
  for (int r = 0; r < 16; r++) {
    int q_local = (r & 3) + 8 * (r >> 2) + 4 * hi;
    float l_r = __shfl(lt_full, q_local);
    float inv = 1.f / l_r;
    int q = q0 + w * 32 + q_local;
    size_t rowbase = ((size_t)(b * S_LEN + q)) * DIM + h * HD;
    O[rowbase + l31] = f2b(oacc[0][r] * inv);
    if (l31 < 16) O[rowbase + 32 + l31] = f2b(oacc[1][r] * inv);
  }
}

// ---------------------------------------------------------------------------
extern "C" void kernel_launch(void* const* d_in, const int* in_sizes, int n_in,
                              void* d_out, int out_size, void* d_ws, size_t ws_size,
                              hipStream_t stream)
{
  const float* x  = (const float*)d_in[0];
  const float* Wq = (const float*)d_in[1];
  const float* bq = (const float*)d_in[2];
  const float* Wk = (const float*)d_in[3];
  const float* bk = (const float*)d_in[4];
  const float* Wv = (const float*)d_in[5];
  const float* bv = (const float*)d_in[6];
  const float* Wo = (const float*)d_in[7];
  const float* bo = (const float*)d_in[8];

  u16* ws   = (u16*)d_ws;
  const size_t qkv_elems = (size_t)BHEADS * S_LEN * HDP;  // 8.39M u16 each
  u16* q_ws = ws;                                         // [bh][s][64] bf16
  u16* k_ws = q_ws + qkv_elems;                           // [bh][s][64] bf16
  u16* v_ws = k_ws + qkv_elems;                           // [bh][d][s]  f16 (V^T)
  u16* x_bf = v_ws + qkv_elems;                           // [8192][768] bf16
  u16* a_ws = x_bf;          // aliased: attn writes after all x_bf reads done
  u16* w_bf = x_bf + (size_t)8192 * DIM;                  // 4x[768][768] bf16

  cvt_f32_bf16<<<dim3(3072), dim3(256), 0, stream>>>(x, x_bf);
  cvt_weights<<<dim3(288, 4), dim3(256), 0, stream>>>(Wq, Wk, Wv, Wo, w_bf);
  u16* wq_bf = w_bf;
  u16* wk_bf = w_bf + (size_t)W_ELEMS;
  u16* wv_bf = w_bf + (size_t)2 * W_ELEMS;
  u16* wo_bf = w_bf + (size_t)3 * W_ELEMS;

  gemm_bt<0><<<dim3(768), dim3(256), 0, stream>>>(x_bf, wq_bf, bq, q_ws, ATT_SCALE);
  gemm_bt<0><<<dim3(768), dim3(256), 0, stream>>>(x_bf, wk_bf, bk, k_ws, 1.0f);
  gemm_bt<2><<<dim3(768), dim3(256), 0, stream>>>(x_bf, wv_bf, bv, v_ws, 1.0f);
  attn_kernel<<<dim3(1024), dim3(256), 0, stream>>>(q_ws, k_ws, v_ws, a_ws);
  gemm_bt<1><<<dim3(768), dim3(256), 0, stream>>>(a_ws, wo_bf, bo, d_out, 1.0f);
}

// Round 5
// 276.436 us; speedup vs baseline: 1.0848x; 1.0848x over previous
//
#include <hip/hip_runtime.h>

typedef __bf16 bf16_t;
typedef bf16_t bf16x8 __attribute__((ext_vector_type(8)));
typedef _Float16 f16_t;
typedef __fp16 hf16x2 __attribute__((ext_vector_type(2)));   // cvt_pkrtz return type
typedef f16_t f16x8 __attribute__((ext_vector_type(8)));
typedef float floatx4 __attribute__((ext_vector_type(4)));
typedef float floatx16 __attribute__((ext_vector_type(16)));

#define S_LEN 2048
#define DIM 768
#define NH 16
#define HD 48
#define HDP 64
#define BHEADS 64          // B * NH
#define ATT_SCALE 0.14433756729740643f  // 1/sqrt(48)
#define W_ELEMS (DIM * DIM)

typedef unsigned short u16;
typedef unsigned int u32;

__device__ __forceinline__ u16 f2b(float f) {
  union { float f; u32 i; } z; z.f = f;
  u32 i = z.i;
  return (u16)((i + 0x7fffu + ((i >> 16) & 1u)) >> 16);  // RNE
}
__device__ __forceinline__ u32 pack2(float a, float b) {
  return (u32)f2b(a) | ((u32)f2b(b) << 16);
}
__device__ __forceinline__ u32 pkrtz2(float a, float b) {   // 2x f32 -> packed f16
  union { hf16x2 h; u32 u; } z;
  z.h = __builtin_amdgcn_cvt_pkrtz(a, b);
  return z.u;
}
// v_permlane32_swap_b32: a' = [a.lanes0-31, b.lanes0-31]; b' = [a.lanes32-63, b.lanes32-63]
__device__ __forceinline__ void pl32swap(u32& a, u32& b) {
  asm("v_permlane32_swap_b32 %0, %1" : "+v"(a), "+v"(b));
}

// ---------------------------------------------------------------------------
// fp32 -> bf16 bulk convert, 8 floats/thread. Used for x (3072 blocks).
// ---------------------------------------------------------------------------
__global__ __launch_bounds__(256) void cvt_f32_bf16(
    const float* __restrict__ src, u16* __restrict__ dst)
{
  int idx = blockIdx.x * 256 + threadIdx.x;
  const float4* s = (const float4*)src;
  float4 a = s[idx * 2], b = s[idx * 2 + 1];
  *(uint4*)&dst[(size_t)idx * 8] =
      make_uint4(pack2(a.x, a.y), pack2(a.z, a.w), pack2(b.x, b.y), pack2(b.z, b.w));
}

// ---------------------------------------------------------------------------
// Convert the 4 weight matrices fp32 -> bf16 once per launch. grid (288, 4).
// ---------------------------------------------------------------------------
__global__ __launch_bounds__(256) void cvt_weights(
    const float* __restrict__ w0, const float* __restrict__ w1,
    const float* __restrict__ w2, const float* __restrict__ w3,
    u16* __restrict__ dst)
{
  const float* srcs[4] = {w0, w1, w2, w3};
  const float* src = srcs[blockIdx.y];
  u16* d = dst + (size_t)blockIdx.y * W_ELEMS;
  int idx = blockIdx.x * 256 + threadIdx.x;
  const float4* s = (const float4*)src;
  float4 a = s[idx * 2], b = s[idx * 2 + 1];
  *(uint4*)&d[(size_t)idx * 8] =
      make_uint4(pack2(a.x, a.y), pack2(a.z, a.w), pack2(b.x, b.y), pack2(b.z, b.w));
}

// ---------------------------------------------------------------------------
// C = (A @ W^T + bias) * scale.  A bf16 [8192][768]; W bf16 [768][768]
// (pre-converted); bias fp32. Tile 128x64, BK=32, 256 threads (4 waves).
// MFMA 16x16x32 bf16.
// OMODE 0: bf16 head-scatter [b*16+h][s][64] (Q,K; only d<48 written)
// OMODE 1: fp32 [row][768] (final output). A is HEAD-MAJOR [bh][s][48]
//          (attn's contiguous output layout); every 8-col chunk lies inside
//          one head (48%8==0) and stays 16B-aligned (96=6*16).
// OMODE 2: f16 V^T [b*16+h][d][s] via LDS-transpose epilogue
// ---------------------------------------------------------------------------
template<int OMODE>
__global__ __launch_bounds__(256) void gemm_bt(
    const u16* __restrict__ A, const u16* __restrict__ W,
    const float* __restrict__ bias, void* __restrict__ outv, float scale)
{
  // As: 128x40 (5120), Bs: 64x40 (2560); T (OMODE 2): 64x136 u16 (8704)
  __shared__ __attribute__((aligned(16))) u16 smem[8704];
  u16 (*As)[40] = (u16(*)[40])smem;
  u16 (*Bs)[40] = (u16(*)[40])(smem + 5120);

  const int tid = threadIdx.x;
  const int w = tid >> 6, lane = tid & 63, lo = lane & 15, quad = lane >> 4;
  const int bm = blockIdx.x & 63, bn = blockIdx.x >> 6;
  const int m0 = bm * 128, n0 = bn * 64;

  floatx4 acc[2][4];
#pragma unroll
  for (int mi = 0; mi < 2; mi++)
#pragma unroll
    for (int ni = 0; ni < 4; ni++) acc[mi][ni] = (floatx4){0.f, 0.f, 0.f, 0.f};

  for (int k0 = 0; k0 < DIM; k0 += 32) {
    // A tile 128x32: 512 chunks, 2/thread
#pragma unroll
    for (int it = 0; it < 2; ++it) {
      int c = tid + it * 256;
      int r = c >> 2, cc = c & 3;
      const u16* src;
      if constexpr (OMODE == 1) {
        int row = m0 + r, c8 = k0 + cc * 8;
        int h = c8 / HD, d = c8 - h * HD;
        int b = row >> 11, s = row & 2047;
        src = &A[((size_t)((b * NH + h) * S_LEN + s)) * HD + d];
      } else {
        src = &A[(size_t)(m0 + r) * DIM + k0 + cc * 8];
      }
      *(uint4*)&As[r][cc * 8] = *(const uint4*)src;
    }
    // W tile 64x32: 256 chunks, 1/thread (pure copy, no conversion)
    {
      int r = tid >> 2, cc = tid & 3;
      *(uint4*)&Bs[r][cc * 8] = *(const uint4*)&W[(size_t)(n0 + r) * DIM + k0 + cc * 8];
    }
    __syncthreads();
    bf16x8 af[2], bfr[4];
#pragma unroll
    for (int mi = 0; mi < 2; mi++) af[mi] = *(const bf16x8*)&As[w * 32 + mi * 16 + lo][quad * 8];
#pragma unroll
    for (int ni = 0; ni < 4; ni++) bfr[ni] = *(const bf16x8*)&Bs[ni * 16 + lo][quad * 8];
#pragma unroll
    for (int mi = 0; mi < 2; mi++)
#pragma unroll
      for (int ni = 0; ni < 4; ni++)
        acc[mi][ni] = __builtin_amdgcn_mfma_f32_16x16x32_bf16(af[mi], bfr[ni], acc[mi][ni], 0, 0, 0);
    __syncthreads();
  }

  if constexpr (OMODE == 2) {
    u16 (*T)[136] = (u16(*)[136])smem;
    u16* out = (u16*)outv;
#pragma unroll
    for (int mi = 0; mi < 2; mi++)
#pragma unroll
      for (int ni = 0; ni < 4; ni++) {
        int col = ni * 16 + lo;
        float bb = bias[n0 + col];
        float v0 = acc[mi][ni][0] + bb, v1 = acc[mi][ni][1] + bb;
        float v2 = acc[mi][ni][2] + bb, v3 = acc[mi][ni][3] + bb;
        *(uint2*)&T[col][w * 32 + mi * 16 + quad * 4] =
            make_uint2(pkrtz2(v0, v1), pkrtz2(v2, v3));
      }
    __syncthreads();
    const int b = m0 >> 11, s0 = m0 & 2047;
#pragma unroll
    for (int it = 0; it < 4; ++it) {
      int ch = tid + it * 256;
      int col = ch >> 4, sc = ch & 15;
      int gcol = n0 + col;
      int h = gcol / HD, d = gcol - h * HD;
      size_t dst = ((size_t)(b * NH + h) * HDP + d) * S_LEN + s0 + sc * 8;
      *(uint4*)&out[dst] = *(const uint4*)&T[col][sc * 8];
    }
    return;
  }

#pragma unroll
  for (int mi = 0; mi < 2; mi++)
#pragma unroll
    for (int ni = 0; ni < 4; ni++)
#pragma unroll
      for (int r = 0; r < 4; r++) {
        int row = m0 + w * 32 + mi * 16 + quad * 4 + r;
        int col = n0 + ni * 16 + lo;
        float v = (acc[mi][ni][r] + bias[col]) * scale;
        if constexpr (OMODE == 1) {
          ((float*)outv)[(size_t)row * DIM + col] = v;
        } else {
          int b = row >> 11, s = row & 2047;
          int h = col / HD, d = col - h * HD;
          ((u16*)outv)[((size_t)((b * NH + h) * S_LEN + s)) * HDP + d] = f2b(v);
        }
      }
}

// ---------------------------------------------------------------------------
// Flash attention, 32x32x16 MFMA, swapped QK^T (mfma(K,Q) -> P[key][q=l31]).
// ROUND 5 = round-3 structure (R=64 q-rows/wave: K/V ds_reads amortized over
// 2 q-subtiles) + XCD read-locality swizzle + HEAD-MAJOR contiguous O-write.
// - grid 512 flat = 2 blocks/CU; xcd = flat&7 -> each XCD owns 8 bh; its K/V
//   working set = 4MB = one XCD L2 (round-4 verified: FETCH 126->30MB).
// - O written [bh][s][48]: 24KB contiguous per block, block-private (no
//   cross-XCD partial-line sharing; round-4's 121MB WRITE_SIZE -> ~13MB).
//   The Wo GEMM (OMODE 1) reads this layout directly.
// - P stays in registers: __expf -> cvt_pkrtz -> v_permlane32_swap_b32.
// - Denominator l in f32 from UNROUNDED p; epilogue completes l(q=l31) via
//   shfl_xor(32) then per-output-row denom via __shfl from lane q_local.
// - K/V double-buffered in LDS, reg-staged issue-early/write-late (T14),
//   ONE barrier per tile. Pitches 56/72 u16 -> conflict-free ds_read_b128.
// LDS: 2*(64*56 + 64*72)*2B = 32 KB.
// ---------------------------------------------------------------------------
#define STG_LOAD(k0n) do {                                                     \
  _Pragma("unroll")                                                            \
  for (int it = 0; it < 3; ++it) {                                             \
    int c = tid + it * 256;                                                    \
    if (c < 384) {                                                             \
      int r = c / 6, cc = c - r * 6;                                           \
      stg[it] = *(const uint4*)&K[base + (size_t)((k0n) + r) * HDP + cc * 8];  \
    } else {                                                                   \
      int c2 = c - 384, r = c2 >> 3, cc = c2 & 7;                              \
      stg[it] = *(const uint4*)&V[base + (size_t)r * S_LEN + (k0n) + cc * 8];  \
    }                                                                          \
  }                                                                            \
} while (0)

#define STG_WRITE(bufi) do {                                                   \
  _Pragma("unroll")                                                            \
  for (int it = 0; it < 3; ++it) {                                             \
    int c = tid + it * 256;                                                    \
    if (c < 384) {                                                             \
      int r = c / 6, cc = c - r * 6;                                           \
      *(uint4*)&Ks[bufi][r][cc * 8] = stg[it];                                 \
    } else {                                                                   \
      int c2 = c - 384, r = c2 >> 3, cc = c2 & 7;                              \
      *(uint4*)&Vt[bufi][r][cc * 8] = stg[it];                                 \
    }                                                                          \
  }                                                                            \
} while (0)

__global__ __launch_bounds__(256, 2) void attn_kernel(
    const u16* __restrict__ Q, const u16* __restrict__ K,
    const u16* __restrict__ V, u16* __restrict__ O)
{
  __shared__ __attribute__((aligned(16))) u16 Ks[2][64][56];  // keys x d(<48)
  __shared__ __attribute__((aligned(16))) u16 Vt[2][64][72];  // d x keys (f16)

  const int tid = threadIdx.x;
  const int w = tid >> 6, lane = tid & 63, l31 = lane & 31, hi = lane >> 5;
  // XCD-locality swizzle: 512 flat blocks; all 8 q-blocks of a bh and 8
  // consecutive bh share one XCD (id%8 = XCD round-robin assumption).
  const int flat = blockIdx.x;
  const int xcd = flat & 7, sub = flat >> 3;          // sub in [0,64)
  const int bh = xcd * 8 + (sub >> 3);                // 8 bh per XCD
  const int q0 = (sub & 7) * 256;                     // 8 q-blocks per bh
  const size_t base = (size_t)bh * S_LEN * HDP;

  // Q fragments (B-operand of swapped QK): Q[q0+w*64+t*32+l31][ks*16+hi*8+j]
  bf16x8 qf[2][3];
#pragma unroll
  for (int t = 0; t < 2; t++)
#pragma unroll
    for (int ks = 0; ks < 3; ks++)
      qf[t][ks] = *(const bf16x8*)
          &Q[base + (size_t)(q0 + w * 64 + t * 32 + l31) * HDP + ks * 16 + hi * 8];

  floatx16 oacc[2][2];
#pragma unroll
  for (int t = 0; t < 2; t++)
#pragma unroll
    for (int nd = 0; nd < 2; nd++)
#pragma unroll
      for (int r = 0; r < 16; r++) oacc[t][nd][r] = 0.f;

  float l_lane[2] = {0.f, 0.f};   // f32 denom for q = l31 (this lane's key half)

  uint4 stg[3];
  STG_LOAD(0);
  STG_WRITE(0);

  for (int ti = 0; ti < 32; ++ti) {
    const int cur = ti & 1;
    if (ti < 31) STG_LOAD((ti + 1) * 64);   // in flight across the barrier (T14)
    __syncthreads();

    // K A-fragments, shared by both q-subtiles
    bf16x8 ak[2][3];
#pragma unroll
    for (int na = 0; na < 2; na++)
#pragma unroll
      for (int ks = 0; ks < 3; ks++)
        ak[na][ks] = *(const bf16x8*)&Ks[cur][na * 32 + l31][ks * 16 + hi * 8];

    // QK^T (swapped) + exp + pack; pk[t][na][m] covers keys
    // na*32 + 8*(m>>1) + 4*hi + 2*(m&1) + {0,1}, all for q = l31.
    u32 pk[2][2][8];
#pragma unroll
    for (int t = 0; t < 2; t++) {
      floatx16 s0, s1;
#pragma unroll
      for (int r = 0; r < 16; r++) { s0[r] = 0.f; s1[r] = 0.f; }
#pragma unroll
      for (int ks = 0; ks < 3; ks++) {
        s0 = __builtin_amdgcn_mfma_f32_32x32x16_bf16(ak[0][ks], qf[t][ks], s0, 0, 0, 0);
        s1 = __builtin_amdgcn_mfma_f32_32x32x16_bf16(ak[1][ks], qf[t][ks], s1, 0, 0, 0);
      }
#pragma unroll
      for (int m = 0; m < 8; m++) {
        float a0 = __expf(s0[2 * m]), a1 = __expf(s0[2 * m + 1]);
        float b0 = __expf(s1[2 * m]), b1 = __expf(s1[2 * m + 1]);
        l_lane[t] += (a0 + a1) + (b0 + b1);
        pk[t][0][m] = pkrtz2(a0, a1);
        pk[t][1][m] = pkrtz2(b0, b1);
      }
    }

    // O += P @ V : A-frag rebuilt in registers via permlane32_swap
#pragma unroll
    for (int kt = 0; kt < 4; kt++) {
      f16x8 bv0 = *(const f16x8*)&Vt[cur][l31][kt * 16 + hi * 8];
      f16x8 bv1 = *(const f16x8*)&Vt[cur][32 + l31][kt * 16 + hi * 8];
      const int na = kt >> 1, k4 = (kt & 1) * 4;
#pragma unroll
      for (int t = 0; t < 2; t++) {
        u32 w0 = pk[t][na][k4 + 0], w2 = pk[t][na][k4 + 2];
        u32 w1 = pk[t][na][k4 + 1], w3 = pk[t][na][k4 + 3];
        pl32swap(w0, w2);
        pl32swap(w1, w3);
        union { u32 u[4]; f16x8 f; } af;
        af.u[0] = w0; af.u[1] = w1; af.u[2] = w2; af.u[3] = w3;
        oacc[t][0] = __builtin_amdgcn_mfma_f32_32x32x16_f16(af.f, bv0, oacc[t][0], 0, 0, 0);
        oacc[t][1] = __builtin_amdgcn_mfma_f32_32x32x16_f16(af.f, bv1, oacc[t][1], 0, 0, 0);
      }
    }

    if (ti < 31) STG_WRITE(cur ^ 1);   // write-late into the other buffer
  }

  // epilogue: complete l(q=l31) across halves, fetch per-output-row denom via
  // __shfl from lane q_local, write HEAD-MAJOR O[bh][q][48] (contiguous 96B
  // rows, block-private -> full-line writes on one XCD).
  const size_t obase = (size_t)bh * S_LEN * HD;
  float lt_full[2];
#pragma unroll
  for (int t = 0; t < 2; t++)
    lt_full[t] = l_lane[t] + __shfl_xor(l_lane[t], 32);
#pragma unroll
  for (int t = 0; t < 2; t++) {
#pragma unroll
    for (int r = 0; r < 16; r++) {
      int q_local = (r & 3) + 8 * (r >> 2) + 4 * hi;
      float l_r = __shfl(lt_full[t], q_local);
      float inv = 1.f / l_r;
      int q = q0 + w * 64 + t * 32 + q_local;
      u16* orow = O + obase + (size_t)q * HD;
      orow[l31] = f2b(oacc[t][0][r] * inv);
      if (l31 < 16) orow[32 + l31] = f2b(oacc[t][1][r] * inv);
    }
  }
}

// ---------------------------------------------------------------------------
extern "C" void kernel_launch(void* const* d_in, const int* in_sizes, int n_in,
                              void* d_out, int out_size, void* d_ws, size_t ws_size,
                              hipStream_t stream)
{
  const float* x  = (const float*)d_in[0];
  const float* Wq = (const float*)d_in[1];
  const float* bq = (const float*)d_in[2];
  const float* Wk = (const float*)d_in[3];
  const float* bk = (const float*)d_in[4];
  const float* Wv = (const float*)d_in[5];
  const float* bv = (const float*)d_in[6];
  const float* Wo = (const float*)d_in[7];
  const float* bo = (const float*)d_in[8];

  u16* ws   = (u16*)d_ws;
  const size_t qkv_elems = (size_t)BHEADS * S_LEN * HDP;  // 8.39M u16 each
  u16* q_ws = ws;                                         // [bh][s][64] bf16
  u16* k_ws = q_ws + qkv_elems;                           // [bh][s][64] bf16
  u16* v_ws = k_ws + qkv_elems;                           // [bh][d][s]  f16 (V^T)
  u16* x_bf = v_ws + qkv_elems;                           // [8192][768] bf16
  u16* a_ws = x_bf;   // aliased: attn writes [bh][s][48] (6.29M u16 = x_bf size)
  u16* w_bf = x_bf + (size_t)8192 * DIM;                  // 4x[768][768] bf16

  cvt_f32_bf16<<<dim3(3072), dim3(256), 0, stream>>>(x, x_bf);
  cvt_weights<<<dim3(288, 4), dim3(256), 0, stream>>>(Wq, Wk, Wv, Wo, w_bf);
  u16* wq_bf = w_bf;
  u16* wk_bf = w_bf + (size_t)W_ELEMS;
  u16* wv_bf = w_bf + (size_t)2 * W_ELEMS;
  u16* wo_bf = w_bf + (size_t)3 * W_ELEMS;

  gemm_bt<0><<<dim3(768), dim3(256), 0, stream>>>(x_bf, wq_bf, bq, q_ws, ATT_SCALE);
  gemm_bt<0><<<dim3(768), dim3(256), 0, stream>>>(x_bf, wk_bf, bk, k_ws, 1.0f);
  gemm_bt<2><<<dim3(768), dim3(256), 0, stream>>>(x_bf, wv_bf, bv, v_ws, 1.0f);
  attn_kernel<<<dim3(512), dim3(256), 0, stream>>>(q_ws, k_ws, v_ws, a_ws);
  gemm_bt<1><<<dim3(768), dim3(256), 0, stream>>>(a_ws, wo_bf, bo, d_out, 1.0f);
}